// Round 1
// baseline (505.619 us; speedup 1.0000x reference)
//
#include <hip/hip_runtime.h>

// Integrate-and-fire, TBN layout. R5: R4 fixed store-ack serialization
// (bitmask epilogue) but sat at 177us = 2.4 TB/s, 39% of achievable BW,
// VALUBusy 10%, VGPR=32. Diagnosis: launch_bounds(256,8) register cap
// left only ~2 loads in flight per wave -> latency/queueing-bound, not
// BW-bound. R5: (a) launch_bounds(256,4) -> 128 VGPR budget,
// (b) 2 float4 columns per thread (idx, idx+256) -> 2 KiB contiguous
// per wave-visit to a time plane, (c) explicit PF=8 prefetch ring ->
// 16 x 1 KiB loads in flight per wave. 16 waves/CU x 16 KiB = 256 KiB
// outstanding per CU.

typedef float v4f __attribute__((ext_vector_type(4)));

#define T_STEPS 32
#define PF 8

__global__ __launch_bounds__(256, 4) void if_kernel(const v4f* __restrict__ x,
                                                    v4f* __restrict__ y,
                                                    int bn4) {
    // Each block owns a contiguous 512-column (8 KiB) span of every plane.
    int base = blockIdx.x * 512 + threadIdx.x;
    if (base >= bn4) return;
    int col2 = base + 256;
    bool has2 = col2 < bn4;
    if (!has2) col2 = base;   // clamp: loads stay in-bounds, stores predicated

    const v4f* xp0 = x + base;
    const v4f* xp1 = x + col2;

    // Membrane state (2 columns x 4 lanes each)
    v4f va = {0.f, 0.f, 0.f, 0.f};
    v4f vb = {0.f, 0.f, 0.f, 0.f};
    // Spike bitmasks, one per scalar lane
    unsigned ma0 = 0u, ma1 = 0u, ma2 = 0u, ma3 = 0u;
    unsigned mb0 = 0u, mb1 = 0u, mb2 = 0u, mb3 = 0u;

    // ---- Prefetch ring: keep PF time-planes (16 loads) in flight ----
    v4f ra[PF], rb[PF];
#pragma unroll
    for (int j = 0; j < PF; ++j) {
        ra[j] = xp0[(size_t)j * bn4];
        rb[j] = xp1[(size_t)j * bn4];
    }

#pragma unroll
    for (int t = 0; t < T_STEPS; ++t) {
        const int s = t & (PF - 1);
        v4f xa = ra[s];
        v4f xb = rb[s];
        if (t + PF < T_STEPS) {
            ra[s] = xp0[(size_t)(t + PF) * bn4];
            rb[s] = xp1[(size_t)(t + PF) * bn4];
        }

        float a0 = va.x + xa.x;
        float a1 = va.y + xa.y;
        float a2 = va.z + xa.z;
        float a3 = va.w + xa.w;
        float b0 = vb.x + xb.x;
        float b1 = vb.y + xb.y;
        float b2 = vb.z + xb.z;
        float b3 = vb.w + xb.w;

        bool sa0 = a0 >= 1.0f;
        bool sa1 = a1 >= 1.0f;
        bool sa2 = a2 >= 1.0f;
        bool sa3 = a3 >= 1.0f;
        bool sb0 = b0 >= 1.0f;
        bool sb1 = b1 >= 1.0f;
        bool sb2 = b2 >= 1.0f;
        bool sb3 = b3 >= 1.0f;

        ma0 |= (unsigned)sa0 << t;
        ma1 |= (unsigned)sa1 << t;
        ma2 |= (unsigned)sa2 << t;
        ma3 |= (unsigned)sa3 << t;
        mb0 |= (unsigned)sb0 << t;
        mb1 |= (unsigned)sb1 << t;
        mb2 |= (unsigned)sb2 << t;
        mb3 |= (unsigned)sb3 << t;

        va.x = sa0 ? a0 - 1.0f : a0;   // soft reset by subtraction
        va.y = sa1 ? a1 - 1.0f : a1;
        va.z = sa2 ? a2 - 1.0f : a2;
        va.w = sa3 ? a3 - 1.0f : a3;
        vb.x = sb0 ? b0 - 1.0f : b0;
        vb.y = sb1 ? b1 - 1.0f : b1;
        vb.z = sb2 ? b2 - 1.0f : b2;
        vb.w = sb3 ? b3 - 1.0f : b3;
    }

    // ---- Epilogue: expand bitmasks, stream all stores wait-free ----
    v4f* yp0 = y + base;
    v4f* yp1 = y + col2;
#pragma unroll
    for (int t = 0; t < T_STEPS; ++t) {
        v4f oa, ob;
        oa.x = ((ma0 >> t) & 1u) ? 1.0f : 0.0f;
        oa.y = ((ma1 >> t) & 1u) ? 1.0f : 0.0f;
        oa.z = ((ma2 >> t) & 1u) ? 1.0f : 0.0f;
        oa.w = ((ma3 >> t) & 1u) ? 1.0f : 0.0f;
        ob.x = ((mb0 >> t) & 1u) ? 1.0f : 0.0f;
        ob.y = ((mb1 >> t) & 1u) ? 1.0f : 0.0f;
        ob.z = ((mb2 >> t) & 1u) ? 1.0f : 0.0f;
        ob.w = ((mb3 >> t) & 1u) ? 1.0f : 0.0f;
        __builtin_nontemporal_store(oa, yp0 + (size_t)t * bn4);
        if (has2) __builtin_nontemporal_store(ob, yp1 + (size_t)t * bn4);
    }
}

extern "C" void kernel_launch(void* const* d_in, const int* in_sizes, int n_in,
                              void* d_out, int out_size, void* d_ws, size_t ws_size,
                              hipStream_t stream) {
    const float* x = (const float*)d_in[0];
    float* y = (float*)d_out;

    int total = in_sizes[0];        // T*B*N = 67,108,864
    int bn = total / T_STEPS;       // B*N  =  2,097,152
    int bn4 = bn / 4;               //        524,288 float4 columns

    int block = 256;
    int threads_needed = (bn4 + 1) / 2;               // 2 columns per thread
    int grid = (threads_needed + block - 1) / block;  // 1024 blocks = 4 per CU

    if_kernel<<<grid, block, 0, stream>>>((const v4f*)x, (v4f*)y, bn4);
}

// Round 2
// 475.107 us; speedup vs baseline: 1.0642x; 1.0642x over previous
//
#include <hip/hip_runtime.h>

// Integrate-and-fire, TBN layout. One thread per 4 consecutive neurons.
// History:
//  R4 (177us, 431MB traffic, VGPR=32): bitmask epilogue killed store-ack
//      serialization; left latency-bound at 2.4 TB/s (~2-3 loads in flight
//      per wave under the 32-VGPR allocation).
//  R5 (213us, 667MB traffic): 2 cols/thread + PF=8 dual-stream ring raised
//      per-byte BW to 3.1 TB/s BUT (a) grid=1024 capped occupancy at 43%,
//      (b) dual interleaved nt-store streams amplified WRITE_SIZE to 1.62x
//      ideal (vs 1.07x for R4's single stream). Net regression.
//  R6: R4 skeleton (1 col/thread, 2048 blocks = 8/CU, single store stream)
//      + single-stream PF=8 prefetch ring. launch_bounds(256,8) caps VGPR
//      at 64 which fits the ring (32 data VGPRs) and keeps 8 blocks/CU.
//      32 waves/CU x 8 x 1KiB = 256 KiB in flight per CU.

typedef float v4f __attribute__((ext_vector_type(4)));

#define T_STEPS 32
#define PF 8

__global__ __launch_bounds__(256, 8) void if_kernel(const v4f* __restrict__ x,
                                                    v4f* __restrict__ y,
                                                    int bn4) {
    int idx = blockIdx.x * blockDim.x + threadIdx.x;
    if (idx >= bn4) return;

    const v4f* xp = x + idx;

    float v0 = 0.f, v1 = 0.f, v2 = 0.f, v3 = 0.f;
    unsigned m0 = 0u, m1 = 0u, m2 = 0u, m3 = 0u;

    // ---- Prefetch ring: PF time-planes (PF x 1KiB per wave) in flight ----
    v4f r[PF];
#pragma unroll
    for (int j = 0; j < PF; ++j) {
        r[j] = xp[(size_t)j * bn4];
    }

    // Main loop: loads only — no store ever enters the vmcnt queue here.
    // Fully unrolled, so r[] indices are all compile-time constants
    // (no scratch; rule: runtime-indexed arrays spill).
#pragma unroll
    for (int t = 0; t < T_STEPS; ++t) {
        const int s = t & (PF - 1);
        v4f xv = r[s];
        if (t + PF < T_STEPS) {
            r[s] = xp[(size_t)(t + PF) * bn4];   // refill ring slot
        }

        float a0 = v0 + xv.x;
        float a1 = v1 + xv.y;
        float a2 = v2 + xv.z;
        float a3 = v3 + xv.w;
        bool s0 = a0 >= 1.0f;
        bool s1 = a1 >= 1.0f;
        bool s2 = a2 >= 1.0f;
        bool s3 = a3 >= 1.0f;
        m0 |= (unsigned)s0 << t;
        m1 |= (unsigned)s1 << t;
        m2 |= (unsigned)s2 << t;
        m3 |= (unsigned)s3 << t;
        v0 = s0 ? a0 - 1.0f : a0;   // soft reset by subtraction
        v1 = s1 ? a1 - 1.0f : a1;
        v2 = s2 ? a2 - 1.0f : a2;
        v3 = s3 ? a3 - 1.0f : a3;
    }

    // ---- Epilogue: expand bitmasks, single sequential nt-store stream ----
    // (R4/R5 A-B showed single stream/thread keeps WRITE_SIZE at ~1.07x
    // ideal; two interleaved streams amplified to 1.62x.)
    v4f* yp = y + idx;
#pragma unroll
    for (int t = 0; t < T_STEPS; ++t) {
        v4f out;
        out.x = ((m0 >> t) & 1u) ? 1.0f : 0.0f;
        out.y = ((m1 >> t) & 1u) ? 1.0f : 0.0f;
        out.z = ((m2 >> t) & 1u) ? 1.0f : 0.0f;
        out.w = ((m3 >> t) & 1u) ? 1.0f : 0.0f;
        __builtin_nontemporal_store(out, yp + (size_t)t * bn4);
    }
}

extern "C" void kernel_launch(void* const* d_in, const int* in_sizes, int n_in,
                              void* d_out, int out_size, void* d_ws, size_t ws_size,
                              hipStream_t stream) {
    const float* x = (const float*)d_in[0];
    float* y = (float*)d_out;

    int total = in_sizes[0];        // T*B*N = 67,108,864
    int bn = total / T_STEPS;       // B*N  =  2,097,152
    int bn4 = bn / 4;               //        524,288 float4 columns

    int block = 256;
    int grid = (bn4 + block - 1) / block;  // 2048 blocks = 8 per CU

    if_kernel<<<grid, block, 0, stream>>>((const v4f*)x, (v4f*)y, bn4);
}